// Round 10
// baseline (306.563 us; speedup 1.0000x reference)
//
#include <hip/hip_runtime.h>
#include <hip/hip_bf16.h>

typedef unsigned short u16;
typedef __attribute__((ext_vector_type(8))) short s8v;
typedef __attribute__((ext_vector_type(4))) short s4v;
typedef __attribute__((ext_vector_type(4))) float f4v;

__device__ __forceinline__ float s2f(u16 s) {
    unsigned int u = ((unsigned int)s) << 16;
    return __builtin_bit_cast(float, u);
}
__device__ __forceinline__ u16 f2s(float f) {
    __hip_bfloat16 h = __float2bfloat16(f);
    return __builtin_bit_cast(u16, h);
}

// async global->LDS DMA, 16 B per lane; LDS dst must be lane-linear
__device__ __forceinline__ void gl2lds16(const u16* g, u16* l) {
    __builtin_amdgcn_global_load_lds((const __attribute__((address_space(1))) void*)g,
                                     (__attribute__((address_space(3))) void*)l, 16, 0, 0);
}

#define BSZ 4
#define DM 1024
#define QLEN 512
#define MLEN 512
#define KLEN 1024
#define DI 4096
#define NH 16
#define DH 64
#define WIN 256   // valid keys: j = i+257 .. i+512 (exactly 256 per query, never clipped)

// ---- fused prep: weight f32->bf16 conversion + z0/z1ss/pos transposes (1 launch) ----
#define CONV_BLKS 13312
#define Z0_BLKS 2048
#define Z1_BLKS 2048
#define POS_BLKS 256
__global__ __launch_bounds__(256) void prep(
    const float* __restrict__ qkv_w, const float* __restrict__ r_w,
    const float* __restrict__ o_w, const float* __restrict__ ff1_w,
    const float* __restrict__ ff2_w,
    u16* __restrict__ wQ, u16* __restrict__ wR, u16* __restrict__ wO,
    u16* __restrict__ wF1, u16* __restrict__ wF2,
    const float* __restrict__ z0, const float* __restrict__ z1ss,
    const float* __restrict__ pos,
    u16* __restrict__ catT, u16* __restrict__ posT)
{
    int bx = blockIdx.x, tid = threadIdx.x;
    if (bx < CONV_BLKS) {
        const int e0 = 786432, e1 = e0 + 262144, e2 = e1 + 262144, e3 = e2 + 1048576;
        int i = bx * 256 + tid;
        const float* s; u16* d; int off;
        if (i < e0)      { s = qkv_w; d = wQ;  off = i; }
        else if (i < e1) { s = r_w;   d = wR;  off = i - e0; }
        else if (i < e2) { s = o_w;   d = wO;  off = i - e1; }
        else if (i < e3) { s = ff1_w; d = wF1; off = i - e2; }
        else             { s = ff2_w; d = wF2; off = i - e3; }
        f4v v = *(const f4v*)&s[(size_t)off * 4];
        s4v o;
#pragma unroll
        for (int k = 0; k < 4; ++k) o[k] = (short)f2s(v[k]);
        *(s4v*)&d[(size_t)off * 4] = o;
        return;
    }
    __shared__ float tile[32][33];
    int tx = tid & 31, ty = tid >> 5;   // (32, 8)
    const float* src; u16* dst; long sS, sD; int ldS, ldD, colOff, rowOff, t0, f0, b;
    if (bx < CONV_BLKS + Z0_BLKS) {
        int idx = bx - CONV_BLKS;
        t0 = (idx & 15) * 32; f0 = ((idx >> 4) & 31) * 32; b = idx >> 9;
        src = z0;   sS = (long)DM * MLEN; ldS = MLEN; colOff = 0;
        dst = catT; sD = (long)KLEN * DM; ldD = DM;  rowOff = 0;
    } else if (bx < CONV_BLKS + Z0_BLKS + Z1_BLKS) {
        int idx = bx - CONV_BLKS - Z0_BLKS;
        t0 = (idx & 15) * 32; f0 = ((idx >> 4) & 31) * 32; b = idx >> 9;
        src = z1ss; sS = (long)DM * QLEN; ldS = QLEN; colOff = 0;
        dst = catT; sD = (long)KLEN * DM; ldD = DM;  rowOff = MLEN;
    } else {
        int idx = bx - CONV_BLKS - Z0_BLKS - Z1_BLKS;
        t0 = (idx & 7) * 32; f0 = (idx >> 3) * 32; b = 0;
        src = pos;  sS = 0; ldS = KLEN; colOff = KLEN - WIN;
        dst = posT; sD = 0; ldD = DM;   rowOff = 0;
    }
#pragma unroll
    for (int p = 0; p < 4; ++p)
        tile[ty + 8 * p][tx] = src[(size_t)b * sS + (size_t)(f0 + ty + 8 * p) * ldS + colOff + t0 + tx];
    __syncthreads();
#pragma unroll
    for (int p = 0; p < 4; ++p)
        dst[(size_t)b * sD + (size_t)(rowOff + t0 + ty + 8 * p) * ldD + f0 + tx] = f2s(tile[tx][ty + 8 * p]);
}

// ---- MFMA GEMM (m97-style): C^T(N x M) = A(M x K, bf16) @ B^T(N x K, bf16) ----
// SPLIT>1: z-th partial -> private f32 buffer (no atomics; consumer sums partials).
// USS=1: uss f32 [b][3072][1024] added in-epilogue; PRE-LOADED into VGPRs before the
//        K-loop so the HBM latency hides under the 16 K-steps of MFMA (T14).
// vTout: for m0 >= 2048 (qkv V-third), write transposed to vTout[m-2048][n] (+uss).
// qskip: Q-third x (t<512) output dead; those blocks early-exit, EXCEPT 32 of the
//        y==0 holes which are remapped as the piggybacked r-gemm (A2/B2/C2, N=256).
template<int BN, int SPLIT, int USS>
__global__ __launch_bounds__(256) void gemm_bt(
    const u16* __restrict__ A,
    const u16* __restrict__ B,
    u16* __restrict__ C,
    float* __restrict__ fOut,
    int M, int K,
    const float* __restrict__ bias,
    int relu,
    int qskip,
    long pstride,
    const float* __restrict__ uss,
    u16* __restrict__ vTout,
    const u16* __restrict__ A2,
    const u16* __restrict__ B2,
    u16* __restrict__ C2,
    float* __restrict__ fOut2,
    long pstride2)
{
    constexpr int BM = 128, BK = 64;
    constexpr int MI = (BN == 128) ? 4 : 2;
    constexpr int NI = 4;
    int n0 = blockIdx.x * BN, m0 = blockIdx.y * BM, Mv = M;
    const u16* Ap = A; const u16* Bp = B; u16* Cp = C;
    bool isR = false;
    if (qskip && m0 + BM <= 1024 && (n0 & 1023) < 512) {
        // dead Q-third x (t<512) block; y==0 holes host the r-gemm (32 blocks)
        if (A2 && blockIdx.y == 0) {
            int rid = (blockIdx.x & 7) | ((blockIdx.x >> 4) << 3);   // 0..31, unique
            isR = true;
            n0 = (rid & 3) * BN;
            m0 = (rid >> 2) * BM;
            Ap = A2; Bp = B2; Cp = C2; Mv = 1024;
        } else return;
    }
    const int Ks = K / SPLIT;
    const int kbeg = blockIdx.z * Ks;
    __shared__ __align__(16) u16 As[BM * BK];
    __shared__ __align__(16) u16 Bs[BN * BK];
    const int tid = threadIdx.x, lane = tid & 63, wv = tid >> 6;
    const int l15 = lane & 15, quad = lane >> 4;
    const int wm = (BN == 128) ? (wv >> 1) * 64 : wv * 32;
    const int wn = (BN == 128) ? (wv & 1) * 64 : 0;

    // USS: issue all epilogue uss loads NOW -- latency hides under the K-loop.
    float uf[MI][NI][4];
    if (USS && !isR) {
#pragma unroll
        for (int mi = 0; mi < MI; ++mi) {
            int m = m0 + wm + mi * 16 + quad * 4;
#pragma unroll
            for (int ni = 0; ni < NI; ++ni) {
                int n = n0 + wn + ni * 16 + l15;
                int b = n >> 10, t = n & 1023;
#pragma unroll
                for (int r2 = 0; r2 < 4; ++r2)
                    uf[mi][ni][r2] = uss[((size_t)b * 3072 + m + r2) * 1024 + t];
            }
        }
    }

    f4v acc[MI][NI] = {};
    for (int kk = kbeg; kk < kbeg + Ks; kk += BK) {
        __syncthreads();
#pragma unroll
        for (int p = 0; p < (BM * 8) / 256; ++p) {
            int c = p * 256 + tid, r = c >> 3, q = c & 7, qs = q ^ (r & 7);
            gl2lds16(&Ap[(size_t)(m0 + r) * K + kk + qs * 8], &As[c * 8]);
        }
#pragma unroll
        for (int p = 0; p < (BN * 8) / 256; ++p) {
            int c = p * 256 + tid, r = c >> 3, q = c & 7, qs = q ^ (r & 7);
            gl2lds16(&Bp[(size_t)(n0 + r) * K + kk + qs * 8], &Bs[c * 8]);
        }
        __syncthreads();
#pragma unroll
        for (int k0 = 0; k0 < BK; k0 += 32) {
            s8v af[MI], bf[NI];
#pragma unroll
            for (int mi = 0; mi < MI; ++mi) {
                int r = wm + mi * 16 + l15;
                af[mi] = *(const s8v*)&As[r * BK + ((((k0 >> 3) + quad) ^ (r & 7)) << 3)];
            }
#pragma unroll
            for (int ni = 0; ni < NI; ++ni) {
                int r = wn + ni * 16 + l15;
                bf[ni] = *(const s8v*)&Bs[r * BK + ((((k0 >> 3) + quad) ^ (r & 7)) << 3)];
            }
#pragma unroll
            for (int mi = 0; mi < MI; ++mi)
#pragma unroll
                for (int ni = 0; ni < NI; ++ni)
                    acc[mi][ni] = __builtin_amdgcn_mfma_f32_16x16x32_bf16(af[mi], bf[ni], acc[mi][ni], 0, 0, 0);
        }
    }
    if (SPLIT > 1) {
        int z = blockIdx.z;
        float* base = (z < 2) ? fOut + (long)z * pstride
                              : fOut2 + (long)(z - 2) * pstride2;
#pragma unroll
        for (int mi = 0; mi < MI; ++mi) {
            int m = m0 + wm + mi * 16 + quad * 4;
#pragma unroll
            for (int ni = 0; ni < NI; ++ni) {
                int n = n0 + wn + ni * 16 + l15;
                *(f4v*)&base[(size_t)n * Mv + m] = acc[mi][ni];   // plain 16B store, no RMW
            }
        }
    } else if (USS && vTout && !isR && m0 >= 2048) {
        // V third of qkv: vT[d][n] = prod + uss (pre-loaded)
#pragma unroll
        for (int mi = 0; mi < MI; ++mi) {
            int m = m0 + wm + mi * 16 + quad * 4;
#pragma unroll
            for (int ni = 0; ni < NI; ++ni) {
                int n = n0 + wn + ni * 16 + l15;
#pragma unroll
                for (int r2 = 0; r2 < 4; ++r2)
                    vTout[(size_t)(m + r2 - 2048) * 4096 + n] = f2s(acc[mi][ni][r2] + uf[mi][ni][r2]);
            }
        }
    } else {
#pragma unroll
        for (int mi = 0; mi < MI; ++mi) {
            int m = m0 + wm + mi * 16 + quad * 4;
            float bv[4] = {0.f, 0.f, 0.f, 0.f};
            if (bias && !isR) {
#pragma unroll
                for (int r2 = 0; r2 < 4; ++r2) bv[r2] = bias[m + r2];
            }
#pragma unroll
            for (int ni = 0; ni < NI; ++ni) {
                int n = n0 + wn + ni * 16 + l15;
                float o[4];
#pragma unroll
                for (int r2 = 0; r2 < 4; ++r2) o[r2] = acc[mi][ni][r2] + bv[r2];
                if (USS && !isR) {
#pragma unroll
                    for (int r2 = 0; r2 < 4; ++r2) o[r2] += uf[mi][ni][r2];
                }
                if (relu && !isR) {
#pragma unroll
                    for (int r2 = 0; r2 < 4; ++r2) o[r2] = fmaxf(o[r2], 0.f);
                }
                s4v st;
#pragma unroll
                for (int r2 = 0; r2 < 4; ++r2) st[r2] = (short)f2s(o[r2]);
                *(s4v*)&Cp[(size_t)n * Mv + m] = st;
            }
        }
    }
}

// ---- MFMA banded flash attention (v5: QT=64, direct-global K/V, XCD-contiguous qt) ----
#define QT 64
#define SROW 260   // f32 row stride: 260 % 32 == 4 -> spreads rows across banks
__global__ __launch_bounds__(256, 2) void attn_mfma(
    const u16* __restrict__ WHT,      // (BSZ, KLEN, 3*DM) bf16 (Q,K thirds valid, uss baked)
    const u16* __restrict__ VT,       // (DM, BSZ*KLEN) bf16 = V^T (+uss), cols n=b*1024+t
    const u16* __restrict__ RT,       // (WIN, DM) bf16
    const float* __restrict__ rwb, const float* __restrict__ rrb,
    u16* __restrict__ avT)            // (BSZ, QLEN, DM) bf16
{
    __shared__ __align__(16) float sS[QT * SROW];   // 66560 B -> 2 blocks/CU

    // T1 XCD swizzle: HW round-robins consecutive flat ids over 8 XCD L2s. Remap so
    // one XCD runs consecutive qt for a given (n,b): adjacent qt share 80% of the
    // K/V window -> L2 hits. nwg = 512 = 8*64, bijective.
    int F = blockIdx.x + 8 * (blockIdx.y + 16 * blockIdx.z);
    int L = (F & 7) * 64 + (F >> 3);
    const int qt = L & 7, n = (L >> 3) & 15, b = L >> 7;

    const int i0 = qt * QT, j0 = i0 + WIN + 1;
    const int tid = threadIdx.x, lane = tid & 63, wv = tid >> 6;
    const int l15 = lane & 15, quad = lane >> 4;
    const u16* W = WHT + (size_t)b * KLEN * (3 * DM);

    // Q fragments for 4 row-sets (A-operand rows = l15 = qi within set), biases baked in
    s8v qac[4][2], qbd[4][2];
#pragma unroll
    for (int h = 0; h < 4; ++h) {
        int qrow = MLEN + i0 + 16 * h + l15;
#pragma unroll
        for (int kc = 0; kc < 2; ++kc) {
            int col = n * DH + kc * 32 + quad * 8;
            s8v qv = *(const s8v*)&W[(size_t)qrow * (3 * DM) + col];
            s8v a, c;
#pragma unroll
            for (int e = 0; e < 8; ++e) {
                float qf = s2f((u16)qv[e]);
                a[e] = (short)f2s(qf + rwb[col + e]);
                c[e] = (short)f2s(qf + rrb[col + e]);
            }
            qac[h][kc] = a; qbd[h][kc] = c;
        }
    }

    // Phase 1: S[qi][t] = AC (QK^T); 20 k-tiles cover c in [0,320)
    for (int ci = wv; ci < 20; ci += 4) {
        int j = j0 + ci * 16 + l15; if (j > KLEN - 1) j = KLEN - 1;
        const u16* Kr = &W[(size_t)j * (3 * DM) + DM + n * DH + quad * 8];
        s8v k0 = *(const s8v*)Kr, k1 = *(const s8v*)(Kr + 32);
#pragma unroll
        for (int h = 0; h < 4; ++h) {
            f4v acc = {};
            acc = __builtin_amdgcn_mfma_f32_16x16x32_bf16(qac[h][0], k0, acc, 0, 0, 0);
            acc = __builtin_amdgcn_mfma_f32_16x16x32_bf16(qac[h][1], k1, acc, 0, 0, 0);
#pragma unroll
            for (int r2 = 0; r2 < 4; ++r2) {
                int qi = 16 * h + quad * 4 + r2;
                int t = ci * 16 + l15 - qi;
                if ((unsigned)t < 256u) sS[qi * SROW + t] = acc[r2];
            }
        }
    }
    __syncthreads();

    // Phase 2: S[qi][t'] += BD (rr_q @ R^T)
#pragma unroll
    for (int cc = 0; cc < 4; ++cc) {
        int ci = wv + cc * 4;
        const u16* Rr = &RT[(size_t)(ci * 16 + l15) * DM + n * DH + quad * 8];
        s8v r0 = *(const s8v*)Rr, r1 = *(const s8v*)(Rr + 32);
#pragma unroll
        for (int h = 0; h < 4; ++h) {
            f4v acc = {};
            acc = __builtin_amdgcn_mfma_f32_16x16x32_bf16(qbd[h][0], r0, acc, 0, 0, 0);
            acc = __builtin_amdgcn_mfma_f32_16x16x32_bf16(qbd[h][1], r1, acc, 0, 0, 0);
#pragma unroll
            for (int r2 = 0; r2 < 4; ++r2) {
                int qi = 16 * h + quad * 4 + r2;
                sS[qi * SROW + ci * 16 + l15] += acc[r2];
            }
        }
    }
    __syncthreads();

    // Phase 3: softmax; P (bf16) in-place at c' = qi + 1 + t'; zeros pad to 320
    {
        int g = tid >> 4, l = tid & 15;
#pragma unroll
        for (int h = 0; h < 4; ++h) {
            int r = g + 16 * h;
            float vals[16], mx = -1e30f;
#pragma unroll
            for (int k = 0; k < 16; ++k) {
                float s = sS[r * SROW + l + 16 * k] * 0.125f;
                vals[k] = s; mx = fmaxf(mx, s);
            }
            asm volatile("" ::: "memory");   // fence: S f32 reads before u16 P writes (aliased)
#pragma unroll
            for (int d = 1; d < 16; d <<= 1) mx = fmaxf(mx, __shfl_xor(mx, d, 16));
            float sum = 0.f;
#pragma unroll
            for (int k = 0; k < 16; ++k) { vals[k] = __expf(vals[k] - mx); sum += vals[k]; }
#pragma unroll
            for (int d = 1; d < 16; d <<= 1) sum += __shfl_xor(sum, d, 16);
            float inv = 1.f / sum;
            u16* sPr = (u16*)&sS[r * SROW];
#pragma unroll
            for (int k = 0; k < 16; ++k) sPr[r + 1 + l + 16 * k] = f2s(vals[k] * inv);
            for (int p = l; p <= r; p += 16) sPr[p] = 0;               // leading zeros [0, r]
            for (int p = r + 257 + l; p < 320; p += 16) sPr[p] = 0;    // trailing [r+257, 320)
        }
    }
    __syncthreads();

    // Phase 4: O = P @ V; V fragment loaded once, used by all 4 row-sets; 10 k-chunks
    const u16* sPu = (const u16*)sS;
    const size_t vbase = (size_t)(n * DH + wv * 16 + l15) * 4096
                       + (size_t)b * KLEN + (j0 - 1) + quad * 8;
    f4v o[4] = {};
#pragma unroll
    for (int kc = 0; kc < 10; ++kc) {
        s8v bb = *(const s8v*)&VT[vbase + kc * 32];
#pragma unroll
        for (int h = 0; h < 4; ++h) {
            s8v a = *(const s8v*)&sPu[(size_t)(16 * h + l15) * (2 * SROW) + kc * 32 + quad * 8];
            o[h] = __builtin_amdgcn_mfma_f32_16x16x32_bf16(a, bb, o[h], 0, 0, 0);
        }
    }
#pragma unroll
    for (int h = 0; h < 4; ++h)
#pragma unroll
        for (int r2 = 0; r2 < 4; ++r2) {
            int qi = quad * 4 + r2;
            avT[((size_t)b * QLEN + i0 + 16 * h + qi) * DM + n * DH + wv * 16 + l15] = f2s(o[h][r2]);
        }
}

// ---- layernorm (mid): out = LN(2 partials + bias + res_bf16) -> bf16 row-major ----
__global__ __launch_bounds__(256) void ln_f(
    const float* __restrict__ P, long pstride, int nparts,
    const float* __restrict__ bias,
    const u16* __restrict__ res, int resMode, u16* __restrict__ out)
{
    int n = blockIdx.x, tid = threadIdx.x;
    int lane = tid & 63, wv = tid >> 6;
    int f = tid * 4;
    int rrow = resMode ? (((n >> 9) * 2 + 1) * 512 + (n & 511)) : n;
    f4v pv = *(const f4v*)&P[(size_t)n * DM + f];
    for (int p = 1; p < nparts; ++p) {
        const float* Pp = P + (long)p * pstride;
        pv += *(const f4v*)&Pp[(size_t)n * DM + f];
    }
    s4v rv = *(const s4v*)&res[(size_t)rrow * DM + f];
    f4v bv = *(const f4v*)&bias[f];
    float v[4];
#pragma unroll
    for (int k = 0; k < 4; ++k) v[k] = pv[k] + bv[k] + s2f((u16)rv[k]);
    float s = v[0] + v[1] + v[2] + v[3];
    float ss = v[0] * v[0] + v[1] * v[1] + v[2] * v[2] + v[3] * v[3];
#pragma unroll
    for (int d = 1; d < 64; d <<= 1) {
        s += __shfl_xor(s, d, 64);
        ss += __shfl_xor(ss, d, 64);
    }
    __shared__ float ps[4], pss[4];
    if (lane == 0) { ps[wv] = s; pss[wv] = ss; }
    __syncthreads();
    float S = ps[0] + ps[1] + ps[2] + ps[3];
    float SS = pss[0] + pss[1] + pss[2] + pss[3];
    float m = S * (1.f / DM);
    float var = SS * (1.f / DM) - m * m;
    float inv = rsqrtf(fmaxf(var, 0.f) + 1e-5f);
    s4v st;
#pragma unroll
    for (int k = 0; k < 4; ++k) st[k] = (short)f2s((v[k] - m) * inv);
    *(s4v*)&out[(size_t)n * DM + f] = st;
}

// ---- final: out_f32[b][f][q] = LN(4 partials + bias + res_bf16), fused transpose ----
#define LNR 16
#define LROW 1030
__global__ __launch_bounds__(256) void ln_out(
    const float* __restrict__ P0, const float* __restrict__ P1,
    const float* __restrict__ P2, const float* __restrict__ P3,
    const float* __restrict__ bias, const u16* __restrict__ res,
    float* __restrict__ out)
{
    __shared__ float rows[LNR * LROW];   // 65920 B
    __shared__ float sm[LNR], si[LNR];
    int n0 = blockIdx.x * LNR;
    int tid = threadIdx.x;
    int r = tid >> 4, l = tid & 15;
    int n = n0 + r;
    float s = 0.f, ss = 0.f;
    for (int k = 0; k < 16; ++k) {
        int f = (l + 16 * k) * 4;
        f4v v = *(const f4v*)&P0[(size_t)n * DM + f];
        v += *(const f4v*)&P1[(size_t)n * DM + f];
        v += *(const f4v*)&P2[(size_t)n * DM + f];
        v += *(const f4v*)&P3[(size_t)n * DM + f];
        s4v rv = *(const s4v*)&res[(size_t)n * DM + f];
        f4v bv = *(const f4v*)&bias[f];
        float* dst = &rows[r * LROW + f];
#pragma unroll
        for (int j = 0; j < 4; ++j) {
            float x = v[j] + bv[j] + s2f((u16)rv[j]);
            dst[j] = x;
            s += x; ss += x * x;
        }
    }
#pragma unroll
    for (int d = 1; d < 16; d <<= 1) {
        s += __shfl_xor(s, d, 16);
        ss += __shfl_xor(ss, d, 16);
    }
    if (l == 0) {
        float m = s * (1.f / DM);
        float var = ss * (1.f / DM) - m * m;
        sm[r] = m; si[r] = rsqrtf(fmaxf(var, 0.f) + 1e-5f);
    }
    __syncthreads();
    // transposed write: out[b][f][q0+qi]
    int b = n0 >> 9, q0 = n0 & 511;
    int qi = tid & 15, g = tid >> 4;
    float m = sm[qi], inv = si[qi];
    float* O = out + (size_t)b * DM * QLEN + q0 + qi;
    for (int k = 0; k < 64; ++k) {
        int f = g + 16 * k;
        O[(size_t)f * QLEN] = (rows[qi * LROW + f] - m) * inv;
    }
}

extern "C" void kernel_launch(void* const* d_in, const int* in_sizes, int n_in,
                              void* d_out, int out_size, void* d_ws, size_t ws_size,
                              hipStream_t stream) {
    const float* z1ss  = (const float*)d_in[0];
    const float* uss   = (const float*)d_in[1];
    const float* z0    = (const float*)d_in[2];
    const float* pos   = (const float*)d_in[3];
    const float* qkv_w = (const float*)d_in[4];
    const float* r_w   = (const float*)d_in[5];
    const float* rwb   = (const float*)d_in[6];
    const float* rrb   = (const float*)d_in[7];
    const float* o_w   = (const float*)d_in[8];
    const float* o_b   = (const float*)d_in[9];
    const float* ff1_w = (const float*)d_in[10];
    const float* ff1_b = (const float*)d_in[11];
    const float* ff2_w = (const float*)d_in[12];
    const float* ff2_b = (const float*)d_in[13];

    u16* ws = (u16*)d_ws;
    u16* wQ   = ws;             // [0,6) MB
    u16* wR   = ws + 3145728;   // [6,8)
    u16* wO   = ws + 4194304;   // [8,10)
    u16* wF1  = ws + 5242880;   // [10,18)
    u16* wF2  = ws + 9437184;   // [18,26)
    u16* catT = ws + 13631488;  // [26,34)  (4,1024,1024)
    u16* whT  = ws + 17825792;  // [34,58)  (4,1024,3072); later aliased as hT
    u16* posT = ws + 30408704;  // [58,58.5)
    u16* rT   = ws + 30670848;  // [58.5,59)
    u16* avT  = ws + 30932992;  // [59,63)  (2048,1024)
    u16* xT   = ws + 33030144;  // [63,67)  (2048,1024)
    float* pref = (float*)(ws + 35127296);  // [67,75) f32 (split partial 0)
    u16* hT   = whT;

    // vT (1024 x 4096 bf16, = 8 MB) aliases pref: live only between qkv gemm and attn.
    u16* vT = (u16*)pref;

    // split partials: p1 at ws+0 (wQ/wR, dead once o-proj/ff2 run);
    // ff2 extras: p2 at byte 8 MB (wO+wF1, dead after ff1), p3 at catT (dead after ln1).
    float* part1 = (float*)d_ws;
    float* part2 = (float*)(ws + 4194304);
    float* part3 = (float*)catT;
    long pstr  = part1 - pref;     // z=0 -> pref, z=1 -> part1
    long pstr2 = part3 - part2;    // z=2 -> part2, z=3 -> part3

    // fused weight-convert + input transposes
    prep<<<CONV_BLKS + Z0_BLKS + Z1_BLKS + POS_BLKS, 256, 0, stream>>>(
        qkv_w, r_w, o_w, ff1_w, ff2_w, wQ, wR, wO, wF1, wF2,
        z0, z1ss, pos, catT, posT);

    // qkv (+uss pre-loaded) + r-gemm in the qskip holes: whT Q/K thirds (+uss);
    // V third -> vT (+uss); rT. Grid exactly 1536 = full single-wave residency.
    gemm_bt<64, 1, 1><<<dim3(64, 24, 1), 256, 0, stream>>>(
        wQ, catT, whT, nullptr, 3 * DM, DM, nullptr, 0, 1, 0, uss, vT,
        wR, posT, rT, nullptr, 0);

    // MFMA banded attention -> avT  (QT=64: 512 blocks, 2/CU, XCD-contiguous qt)
    attn_mfma<<<dim3(QLEN / QT, NH, BSZ), 256, 0, stream>>>(whT, vT, rT, rwb, rrb, avT);

    // o-proj split-2, private partials (overwrites pref/vT: attn already consumed vT)
    gemm_bt<64, 2, 0><<<dim3(32, 8, 2), 256, 0, stream>>>(
        wO, avT, nullptr, pref, DM, DM, nullptr, 0, 0, pstr, nullptr, nullptr,
        nullptr, nullptr, nullptr, nullptr, 0);

    ln_f<<<2048, 256, 0, stream>>>(pref, pstr, 2, o_b, catT, 1, xT);

    // ff1
    gemm_bt<64, 1, 0><<<dim3(32, 32, 1), 256, 0, stream>>>(
        wF1, xT, hT, nullptr, DI, DM, ff1_b, 1, 0, 0, nullptr, nullptr,
        nullptr, nullptr, nullptr, nullptr, 0);

    // ff2 split-4, private partials (pref, part1, part2, part3)
    gemm_bt<64, 4, 0><<<dim3(32, 8, 4), 256, 0, stream>>>(
        wF2, hT, nullptr, pref, DM, DI, nullptr, 0, 0, pstr, nullptr, nullptr,
        nullptr, nullptr, nullptr, part2, pstr2);

    // final LN + transposed f32 output
    ln_out<<<2048 / LNR, 256, 0, stream>>>(
        pref, part1, part2, part3, ff2_b, xT, (float*)d_out);
}